// Round 2
// baseline (128.381 us; speedup 1.0000x reference)
//
#include <hip/hip_runtime.h>
#include <math.h>

// Problem constants
#define NU 32          // users / first dim
#define NSYM 14
#define NSC 3072
#define NRB 256
#define NUS 448        // NU*NSYM
#define NPOINT 114688  // NUS*NRB
#define PLANE 114688   // points per (r,t) plane
#define NC 32          // codebook size

// beta = 4.4492*0.0625 + 4.5655*0.25 + 1.2982 = 2.71765
#define BETA 2.71765f
#define INV_BETA (1.0f/2.71765f)

// ws layout (floats):
//   [0..15]  : Gram matrix G (4 diag reals, then 6 pairs re/im: (0,1),(0,2),(0,3),(1,2),(1,3),(2,3))
//   [64.. ]  : hrb as float2, 8 planes * 114688 points, plane k=(r*4+t),
//              point index = rb*448 + (u*14+sym)

// ---------------------------------------------------------------------------
// Kernel 1: RB averaging + transpose.  Grid 1024 = (u=32) x (k=8) x (rbchunk=4)
// Each block: fixed (u,k), 64 rb, all 14 sym. Reads 14*768 consecutive floats
// per array (float4, coalesced), LDS-transposes, writes runs of 14 float2.
// ---------------------------------------------------------------------------
__global__ __launch_bounds__(256) void k1_rbavg(const float* __restrict__ hre,
                                                const float* __restrict__ him,
                                                float2* __restrict__ hrb,
                                                float* __restrict__ G) {
    __shared__ float2 tile[14][65];   // padded: write-phase reads stride 14 conflict-free

    const int b = blockIdx.x;       // ((u*8 + k)*4 + chunk)
    const int chunk = b & 3;
    const int uk = b >> 2;          // u*8 + k
    const int k = uk & 7;
    const int u = uk >> 3;
    const int rb0 = chunk * 64;
    const int tid = threadIdx.x;

    if (b == 0 && tid < 16) G[tid] = 0.0f;   // k2 accumulates after k1 (stream order)

    const int rb = tid & 63;
    const int s0 = tid >> 6;        // 0..3
    const size_t base_uk = (size_t)uk * (size_t)(NSYM * NSC);

    for (int sym = s0; sym < NSYM; sym += 4) {
        size_t base = base_uk + (size_t)sym * NSC + (size_t)(rb0 + rb) * 12;
        const float4* pr = (const float4*)(hre + base);
        const float4* pi = (const float4*)(him + base);
        float4 r0 = pr[0], r1 = pr[1], r2 = pr[2];
        float4 i0 = pi[0], i1 = pi[1], i2 = pi[2];
        float sre = ((r0.x + r0.y) + (r0.z + r0.w) + (r1.x + r1.y) +
                     (r1.z + r1.w) + (r2.x + r2.y) + (r2.z + r2.w)) * (1.0f / 12.0f);
        float sim = ((i0.x + i0.y) + (i0.z + i0.w) + (i1.x + i1.y) +
                     (i1.z + i1.w) + (i2.x + i2.y) + (i2.z + i2.w)) * (1.0f / 12.0f);
        tile[sym][rb] = make_float2(sre, sim);
    }
    __syncthreads();

    // write phase: 896 float2 per block; consecutive tid -> consecutive sym
    for (int w = tid; w < 64 * NSYM; w += 256) {
        int rbw = w / NSYM;
        int sym = w - rbw * NSYM;
        int idx2 = k * PLANE + (rb0 + rbw) * NUS + u * NSYM + sym;
        hrb[idx2] = tile[sym][rbw];
    }
}

// ---------------------------------------------------------------------------
// Kernel 2: Gram matrix G[t][t'] = sum_{points,r} hrb[r,t]*conj(hrb[r,t'])
// Grid 448 x 256 (one thread per point). Wave shuffle reduce + atomicAdd.
// ---------------------------------------------------------------------------
__global__ __launch_bounds__(256) void k2_gram(const float2* __restrict__ hrb,
                                               float* __restrict__ G) {
    const int p = blockIdx.x * 256 + threadIdx.x;
    float2 x[8];
#pragma unroll
    for (int k = 0; k < 8; k++) x[k] = hrb[k * PLANE + p];

    float acc[16];
#pragma unroll
    for (int t = 0; t < 4; t++) {
        acc[t] = x[t].x * x[t].x + x[t].y * x[t].y +
                 x[4 + t].x * x[4 + t].x + x[4 + t].y * x[4 + t].y;
    }
    const int pa[6] = {0, 0, 0, 1, 1, 2};
    const int pb[6] = {1, 2, 3, 2, 3, 3};
#pragma unroll
    for (int q = 0; q < 6; q++) {
        int a = pa[q], bb = pb[q];
        // x_a * conj(x_b), summed over r (planes a,b and 4+a,4+b)
        float re = x[a].x * x[bb].x + x[a].y * x[bb].y +
                   x[4 + a].x * x[4 + bb].x + x[4 + a].y * x[4 + bb].y;
        float im = x[a].y * x[bb].x - x[a].x * x[bb].y +
                   x[4 + a].y * x[4 + bb].x - x[4 + a].x * x[4 + bb].y;
        acc[4 + 2 * q] = re;
        acc[5 + 2 * q] = im;
    }

    // wave (64-lane) reduction
#pragma unroll
    for (int m = 1; m < 64; m <<= 1) {
#pragma unroll
        for (int i = 0; i < 16; i++) acc[i] += __shfl_xor(acc[i], m);
    }

    __shared__ float red[4][16];
    const int lane = threadIdx.x & 63;
    const int wv = threadIdx.x >> 6;
    if (lane == 0) {
#pragma unroll
        for (int i = 0; i < 16; i++) red[wv][i] = acc[i];
    }
    __syncthreads();
    if (threadIdx.x < 16) {
        float v = red[0][threadIdx.x] + red[1][threadIdx.x] +
                  red[2][threadIdx.x] + red[3][threadIdx.x];
        atomicAdd(&G[threadIdx.x], v);
    }
}

// ---------------------------------------------------------------------------
// Kernel 3: per-rb rate for all 32 precoders, argmax, outputs.
// Grid 256 (one block per rb) x 512 threads (16 threads per codebook c).
// ---------------------------------------------------------------------------
__global__ __launch_bounds__(512) void k3_rate(const float2* __restrict__ hrb,
                                               const float* __restrict__ G,
                                               float* __restrict__ out,
                                               int out_size) {
    __shared__ float2 tile[NUS * 9];   // [us*9 + k], slot 8 = pad (conflict-free)
    __shared__ float nv_s[NC];
    __shared__ float cbr_s[NC][4], cbi_s[NC][4];
    __shared__ float rate_s[NC];

    const int rb = blockIdx.x;
    const int tid = threadIdx.x;

    if (tid < NC) {
        const int l = tid >> 2, n = tid & 3;
        float wr, wi;
        const float SQ = 0.70710678118654752f;
        switch (l) {
            case 0: wr = 1.f;  wi = 0.f;  break;
            case 1: wr = SQ;   wi = SQ;   break;
            case 2: wr = 0.f;  wi = 1.f;  break;
            case 3: wr = -SQ;  wi = SQ;   break;
            case 4: wr = -1.f; wi = 0.f;  break;
            case 5: wr = -SQ;  wi = -SQ;  break;
            case 6: wr = 0.f;  wi = -1.f; break;
            default: wr = SQ;  wi = -SQ;  break;
        }
        float phr = (n == 0) ? 1.f : (n == 2) ? -1.f : 0.f;
        float phi = (n == 1) ? 1.f : (n == 3) ? -1.f : 0.f;
        cbr_s[tid][0] = 1.f;  cbi_s[tid][0] = 0.f;
        cbr_s[tid][1] = wr;   cbi_s[tid][1] = wi;
        cbr_s[tid][2] = phr;  cbi_s[tid][2] = phi;
        cbr_s[tid][3] = phr * wr - phi * wi;
        cbi_s[tid][3] = phr * wi + phi * wr;

        // n_var[c] = (sum_t G_tt + 2*sum_{t<t'} Re(cb_t conj(cb_t') G[t,t'])) / (NPOINT*10)
        float s = G[0] + G[1] + G[2] + G[3];
        const int pa[6] = {0, 0, 0, 1, 1, 2};
        const int pb[6] = {1, 2, 3, 2, 3, 3};
#pragma unroll
        for (int q = 0; q < 6; q++) {
            float gre = G[4 + 2 * q], gim = G[5 + 2 * q];
            float car = cbr_s[tid][pa[q]], cai = cbi_s[tid][pa[q]];
            float cbrx = cbr_s[tid][pb[q]], cbix = cbi_s[tid][pb[q]];
            float zr = car * cbrx + cai * cbix;   // cb_a * conj(cb_b)
            float zi = cai * cbrx - car * cbix;
            s += 2.0f * (zr * gre - zi * gim);
        }
        nv_s[tid] = s * (1.0f / (114688.0f * 10.0f));
    }

    // stage this rb's 448 points x 8 planes into LDS
    for (int idx = tid; idx < NUS * 8; idx += 512) {
        int k = idx / NUS;
        int us = idx - k * NUS;
        tile[us * 9 + k] = hrb[k * PLANE + rb * NUS + us];
    }
    __syncthreads();

    const int c = tid >> 4;
    const int j = tid & 15;
    float cr[4], ci[4];
#pragma unroll
    for (int t = 0; t < 4; t++) { cr[t] = cbr_s[c][t]; ci[t] = cbi_s[c][t]; }
    const float nv = nv_s[c];

    float sum = 0.0f;
    for (int us = j; us < NUS; us += 16) {
        const float2* pt = &tile[us * 9];
        float h0r = 0.f, h0i = 0.f, h1r = 0.f, h1i = 0.f;
#pragma unroll
        for (int t = 0; t < 4; t++) {
            float2 a0 = pt[t], a1 = pt[4 + t];
            h0r += cr[t] * a0.x - ci[t] * a0.y;
            h0i += cr[t] * a0.y + ci[t] * a0.x;
            h1r += cr[t] * a1.x - ci[t] * a1.y;
            h1i += cr[t] * a1.y + ci[t] * a1.x;
        }
        float a = h0r * h0r + h0i * h0i + h1r * h1r + h1i * h1i;
        float Sr = h0r + h1r, Si = h0i + h1i;
        float p = Sr * Sr + Si * Si;
        float Q = a * a + nv * p;
        float den = nv * (a * a * a + 2.0f * a * nv * p + 2.0f * nv * nv * p);
        float sinr = (Q * Q) / den;
        sum += expf(-sinr * INV_BETA);
    }
    // reduce over the 16-lane group
#pragma unroll
    for (int m = 8; m >= 1; m >>= 1) sum += __shfl_xor(sum, m, 16);

    if (j == 0) {
        float es = sum * (1.0f / 448.0f);
        float avg = -BETA * logf(es);
        rate_s[c] = 0.83f * log2f(1.0f + 0.73f * avg);
    }
    __syncthreads();

    if (tid == 0) {
        float best = rate_s[0];
        int bc = 0;
        for (int cc = 1; cc < NC; cc++) {
            if (rate_s[cc] > best) { best = rate_s[cc]; bc = cc; }
        }
        if (rb < out_size) out[rb] = (float)bc;                  // PMI
        if (NRB + rb < out_size) out[NRB + rb] = best;           // rate_for_selected

        // Output 2 layout depends on how the harness flattened complex64:
        //   out_size >= 2560  -> complex viewed as interleaved (re,im) float pairs
        //   else (e.g. 1536)  -> astype(float32): real part only
        if (out_size >= 2 * NRB + 8 * NRB) {
#pragma unroll
            for (int t = 0; t < 4; t++) {
                int o = 2 * NRB + (rb * 4 + t) * 2;
                out[o] = 0.5f * cbr_s[bc][t];
                out[o + 1] = 0.5f * cbi_s[bc][t];
            }
        } else {
#pragma unroll
            for (int t = 0; t < 4; t++) {
                int o = 2 * NRB + rb * 4 + t;
                if (o < out_size) out[o] = 0.5f * cbr_s[bc][t];
            }
        }
    }
}

extern "C" void kernel_launch(void* const* d_in, const int* in_sizes, int n_in,
                              void* d_out, int out_size, void* d_ws, size_t ws_size,
                              hipStream_t stream) {
    const float* hre = (const float*)d_in[0];
    const float* him = (const float*)d_in[1];
    float* out = (float*)d_out;

    float* ws = (float*)d_ws;
    float* G = ws;                          // 16 floats
    float2* hrb = (float2*)(ws + 64);       // 8 * 114688 float2 = 7.34 MB

    k1_rbavg<<<1024, 256, 0, stream>>>(hre, him, hrb, G);
    k2_gram<<<448, 256, 0, stream>>>(hrb, G);
    k3_rate<<<256, 512, 0, stream>>>(hrb, G, out, out_size);
}

// Round 3
// 126.895 us; speedup vs baseline: 1.0117x; 1.0117x over previous
//
#include <hip/hip_runtime.h>
#include <math.h>

// Problem constants
#define NU 32          // users / first dim
#define NSYM 14
#define NSC 3072
#define NRB 256
#define NUS 448        // NU*NSYM
#define NPOINT 114688  // NUS*NRB
#define PLANE 114688   // points per (r,t) plane
#define NC 32          // codebook size

// beta = 4.4492*0.0625 + 4.5655*0.25 + 1.2982 = 2.71765
#define BETA 2.71765f
#define INV_BETA (1.0f/2.71765f)

// ws layout (floats):
//   [0..15]     : Gram matrix G (4 diag reals, then 6 pairs re/im:
//                 (0,1),(0,2),(0,3),(1,2),(1,3),(2,3))
//   [64..1855]  : per-block Gram partials, 112 blocks x 16 floats
//   [4096.. ]   : hrb as float2, 8 planes * 114688 points, plane k=(r*4+t),
//                 point index = rb*448 + (u*14+sym)

// ---------------------------------------------------------------------------
// Kernel 1: RB averaging + transpose.  Grid 1024 = (u=32) x (k=8) x (rbchunk=4)
// Each block: fixed (u,k), 64 rb, all 14 sym. Reads 14*768 consecutive floats
// per array (float4, coalesced), LDS-transposes, writes runs of 14 float2.
// ---------------------------------------------------------------------------
__global__ __launch_bounds__(256) void k1_rbavg(const float* __restrict__ hre,
                                                const float* __restrict__ him,
                                                float2* __restrict__ hrb) {
    __shared__ float2 tile[14][65];   // padded: write-phase reads stride 14 conflict-free

    const int b = blockIdx.x;       // ((u*8 + k)*4 + chunk)
    const int chunk = b & 3;
    const int uk = b >> 2;          // u*8 + k
    const int k = uk & 7;
    const int u = uk >> 3;
    const int rb0 = chunk * 64;
    const int tid = threadIdx.x;

    const int rb = tid & 63;
    const int s0 = tid >> 6;        // 0..3
    const size_t base_uk = (size_t)uk * (size_t)(NSYM * NSC);

    for (int sym = s0; sym < NSYM; sym += 4) {
        size_t base = base_uk + (size_t)sym * NSC + (size_t)(rb0 + rb) * 12;
        const float4* pr = (const float4*)(hre + base);
        const float4* pi = (const float4*)(him + base);
        float4 r0 = pr[0], r1 = pr[1], r2 = pr[2];
        float4 i0 = pi[0], i1 = pi[1], i2 = pi[2];
        float sre = ((r0.x + r0.y) + (r0.z + r0.w) + (r1.x + r1.y) +
                     (r1.z + r1.w) + (r2.x + r2.y) + (r2.z + r2.w)) * (1.0f / 12.0f);
        float sim = ((i0.x + i0.y) + (i0.z + i0.w) + (i1.x + i1.y) +
                     (i1.z + i1.w) + (i2.x + i2.y) + (i2.z + i2.w)) * (1.0f / 12.0f);
        tile[sym][rb] = make_float2(sre, sim);
    }
    __syncthreads();

    // write phase: 896 float2 per block; consecutive tid -> consecutive sym
    for (int w = tid; w < 64 * NSYM; w += 256) {
        int rbw = w / NSYM;
        int sym = w - rbw * NSYM;
        int idx2 = k * PLANE + (rb0 + rbw) * NUS + u * NSYM + sym;
        hrb[idx2] = tile[sym][rbw];
    }
}

// ---------------------------------------------------------------------------
// Kernel 2: Gram partials. Grid 112 x 512, 2 points/thread (112*1024=114688).
// Block-level shuffle+LDS reduction -> partials[block][16]. NO atomics.
// ---------------------------------------------------------------------------
__global__ __launch_bounds__(512) void k2_gram(const float2* __restrict__ hrb,
                                               float* __restrict__ partials) {
    const int tid = threadIdx.x;
    const int pa[6] = {0, 0, 0, 1, 1, 2};
    const int pb[6] = {1, 2, 3, 2, 3, 3};

    float acc[16];
#pragma unroll
    for (int i = 0; i < 16; i++) acc[i] = 0.0f;

#pragma unroll
    for (int it = 0; it < 2; it++) {
        const int p = blockIdx.x * 1024 + it * 512 + tid;
        float2 x[8];
#pragma unroll
        for (int k = 0; k < 8; k++) x[k] = hrb[k * PLANE + p];

#pragma unroll
        for (int t = 0; t < 4; t++) {
            acc[t] += x[t].x * x[t].x + x[t].y * x[t].y +
                      x[4 + t].x * x[4 + t].x + x[4 + t].y * x[4 + t].y;
        }
#pragma unroll
        for (int q = 0; q < 6; q++) {
            int a = pa[q], bb = pb[q];
            float re = x[a].x * x[bb].x + x[a].y * x[bb].y +
                       x[4 + a].x * x[4 + bb].x + x[4 + a].y * x[4 + bb].y;
            float im = x[a].y * x[bb].x - x[a].x * x[bb].y +
                       x[4 + a].y * x[4 + bb].x - x[4 + a].x * x[4 + bb].y;
            acc[4 + 2 * q] += re;
            acc[5 + 2 * q] += im;
        }
    }

    // 64-lane wave reduction
#pragma unroll
    for (int m = 1; m < 64; m <<= 1) {
#pragma unroll
        for (int i = 0; i < 16; i++) acc[i] += __shfl_xor(acc[i], m);
    }

    __shared__ float red[8][16];
    const int lane = threadIdx.x & 63;
    const int wv = threadIdx.x >> 6;   // 0..7
    if (lane == 0) {
#pragma unroll
        for (int i = 0; i < 16; i++) red[wv][i] = acc[i];
    }
    __syncthreads();
    if (tid < 16) {
        float v = 0.0f;
#pragma unroll
        for (int w = 0; w < 8; w++) v += red[w][tid];
        partials[blockIdx.x * 16 + tid] = v;
    }
}

// ---------------------------------------------------------------------------
// Kernel 2b: reduce 112 partials -> G[16]. 1 block x 256 threads.
// ---------------------------------------------------------------------------
__global__ __launch_bounds__(256) void k2b_reduce(const float* __restrict__ partials,
                                                  float* __restrict__ G) {
    const int tid = threadIdx.x;
    const int i = tid & 15;
    const int seg = tid >> 4;      // 0..15, each owns 7 partial rows
    float s = 0.0f;
#pragma unroll
    for (int m = 0; m < 7; m++) s += partials[(seg * 7 + m) * 16 + i];
    __shared__ float red[16][17];
    red[seg][i] = s;
    __syncthreads();
    if (tid < 16) {
        float v = 0.0f;
#pragma unroll
        for (int g = 0; g < 16; g++) v += red[g][tid];
        G[tid] = v;
    }
}

// ---------------------------------------------------------------------------
// Kernel 3: per-rb rate for all 32 precoders, argmax, outputs.
// Grid 256 (one block per rb) x 512 threads (16 threads per codebook c).
// ---------------------------------------------------------------------------
__global__ __launch_bounds__(512) void k3_rate(const float2* __restrict__ hrb,
                                               const float* __restrict__ G,
                                               float* __restrict__ out,
                                               int out_size) {
    __shared__ float2 tile[NUS * 9];   // [us*9 + k], slot 8 = pad (conflict-free)
    __shared__ float nv_s[NC];
    __shared__ float cbr_s[NC][4], cbi_s[NC][4];
    __shared__ float rate_s[NC];

    const int rb = blockIdx.x;
    const int tid = threadIdx.x;

    if (tid < NC) {
        const int l = tid >> 2, n = tid & 3;
        float wr, wi;
        const float SQ = 0.70710678118654752f;
        switch (l) {
            case 0: wr = 1.f;  wi = 0.f;  break;
            case 1: wr = SQ;   wi = SQ;   break;
            case 2: wr = 0.f;  wi = 1.f;  break;
            case 3: wr = -SQ;  wi = SQ;   break;
            case 4: wr = -1.f; wi = 0.f;  break;
            case 5: wr = -SQ;  wi = -SQ;  break;
            case 6: wr = 0.f;  wi = -1.f; break;
            default: wr = SQ;  wi = -SQ;  break;
        }
        float phr = (n == 0) ? 1.f : (n == 2) ? -1.f : 0.f;
        float phi = (n == 1) ? 1.f : (n == 3) ? -1.f : 0.f;
        cbr_s[tid][0] = 1.f;  cbi_s[tid][0] = 0.f;
        cbr_s[tid][1] = wr;   cbi_s[tid][1] = wi;
        cbr_s[tid][2] = phr;  cbi_s[tid][2] = phi;
        cbr_s[tid][3] = phr * wr - phi * wi;
        cbi_s[tid][3] = phr * wi + phi * wr;

        // n_var[c] = (sum_t G_tt + 2*sum_{t<t'} Re(cb_t conj(cb_t') G[t,t'])) / (NPOINT*10)
        float s = G[0] + G[1] + G[2] + G[3];
        const int pa[6] = {0, 0, 0, 1, 1, 2};
        const int pb[6] = {1, 2, 3, 2, 3, 3};
#pragma unroll
        for (int q = 0; q < 6; q++) {
            float gre = G[4 + 2 * q], gim = G[5 + 2 * q];
            float car = cbr_s[tid][pa[q]], cai = cbi_s[tid][pa[q]];
            float cbrx = cbr_s[tid][pb[q]], cbix = cbi_s[tid][pb[q]];
            float zr = car * cbrx + cai * cbix;   // cb_a * conj(cb_b)
            float zi = cai * cbrx - car * cbix;
            s += 2.0f * (zr * gre - zi * gim);
        }
        nv_s[tid] = s * (1.0f / (114688.0f * 10.0f));
    }

    // stage this rb's 448 points x 8 planes into LDS
    for (int idx = tid; idx < NUS * 8; idx += 512) {
        int k = idx / NUS;
        int us = idx - k * NUS;
        tile[us * 9 + k] = hrb[k * PLANE + rb * NUS + us];
    }
    __syncthreads();

    const int c = tid >> 4;
    const int j = tid & 15;
    float cr[4], ci[4];
#pragma unroll
    for (int t = 0; t < 4; t++) { cr[t] = cbr_s[c][t]; ci[t] = cbi_s[c][t]; }
    const float nv = nv_s[c];

    float sum = 0.0f;
    for (int us = j; us < NUS; us += 16) {
        const float2* pt = &tile[us * 9];
        float h0r = 0.f, h0i = 0.f, h1r = 0.f, h1i = 0.f;
#pragma unroll
        for (int t = 0; t < 4; t++) {
            float2 a0 = pt[t], a1 = pt[4 + t];
            h0r += cr[t] * a0.x - ci[t] * a0.y;
            h0i += cr[t] * a0.y + ci[t] * a0.x;
            h1r += cr[t] * a1.x - ci[t] * a1.y;
            h1i += cr[t] * a1.y + ci[t] * a1.x;
        }
        float a = h0r * h0r + h0i * h0i + h1r * h1r + h1i * h1i;
        float Sr = h0r + h1r, Si = h0i + h1i;
        float p = Sr * Sr + Si * Si;
        float Q = a * a + nv * p;
        float den = nv * (a * a * a + 2.0f * a * nv * p + 2.0f * nv * nv * p);
        float sinr = (Q * Q) / den;
        sum += expf(-sinr * INV_BETA);
    }
    // reduce over the 16-lane group
#pragma unroll
    for (int m = 8; m >= 1; m >>= 1) sum += __shfl_xor(sum, m, 16);

    if (j == 0) {
        float es = sum * (1.0f / 448.0f);
        float avg = -BETA * logf(es);
        rate_s[c] = 0.83f * log2f(1.0f + 0.73f * avg);
    }
    __syncthreads();

    if (tid == 0) {
        float best = rate_s[0];
        int bc = 0;
        for (int cc = 1; cc < NC; cc++) {
            if (rate_s[cc] > best) { best = rate_s[cc]; bc = cc; }
        }
        if (rb < out_size) out[rb] = (float)bc;                  // PMI
        if (NRB + rb < out_size) out[NRB + rb] = best;           // rate_for_selected

        // Output 2 layout depends on how the harness flattened complex64:
        //   out_size >= 2560  -> complex viewed as interleaved (re,im) float pairs
        //   else (e.g. 1536)  -> astype(float32): real part only
        if (out_size >= 2 * NRB + 8 * NRB) {
#pragma unroll
            for (int t = 0; t < 4; t++) {
                int o = 2 * NRB + (rb * 4 + t) * 2;
                out[o] = 0.5f * cbr_s[bc][t];
                out[o + 1] = 0.5f * cbi_s[bc][t];
            }
        } else {
#pragma unroll
            for (int t = 0; t < 4; t++) {
                int o = 2 * NRB + rb * 4 + t;
                if (o < out_size) out[o] = 0.5f * cbr_s[bc][t];
            }
        }
    }
}

extern "C" void kernel_launch(void* const* d_in, const int* in_sizes, int n_in,
                              void* d_out, int out_size, void* d_ws, size_t ws_size,
                              hipStream_t stream) {
    const float* hre = (const float*)d_in[0];
    const float* him = (const float*)d_in[1];
    float* out = (float*)d_out;

    float* ws = (float*)d_ws;
    float* G = ws;                          // 16 floats
    float* partials = ws + 64;              // 112*16 floats
    float2* hrb = (float2*)(ws + 4096);     // 8 * 114688 float2 = 7.34 MB

    k1_rbavg<<<1024, 256, 0, stream>>>(hre, him, hrb);
    k2_gram<<<112, 512, 0, stream>>>(hrb, partials);
    k2b_reduce<<<1, 256, 0, stream>>>(partials, G);
    k3_rate<<<256, 512, 0, stream>>>(hrb, G, out, out_size);
}

// Round 4
// 120.619 us; speedup vs baseline: 1.0644x; 1.0520x over previous
//
#include <hip/hip_runtime.h>
#include <math.h>

// Problem constants
#define NU 32          // users
#define NSYM 14
#define NSC 3072
#define NRB 256
#define NUS 448        // NU*NSYM
#define PLANE 114688   // points per (r,t) plane = NRB*NUS
#define NC 32          // codebook size

// beta = 4.4492*0.0625 + 4.5655*0.25 + 1.2982 = 2.71765
#define BETA 2.71765f
#define INV_BETA (1.0f/2.71765f)

// k1_fused tiling: 512 blocks = (u:32) x (chunk:16), 16 rb per chunk
#define CRB 16          // rb per block
#define TP 17           // LDS pitch per sym row (16 rb + 1 pad)
#define TR (NSYM*TP)    // 238 float2 per plane row

// ws layout (floats):
//   [0..8191]   : Gram partials, 512 blocks x 16 floats
//   [8192.. ]   : hrb as float2, 8 planes * 114688 points, plane k=(r*4+t),
//                 point index = rb*448 + (u*14+sym)

// ---------------------------------------------------------------------------
// Kernel 1 (fused): RB-average + transpose writeout + per-block Gram partial.
// Block owns (u, 16 rb) for ALL 8 (r,t) planes, all 14 sym.
// 256 threads: rb = tid&15, k = (tid>>4)&7, half = tid>>7 (sym 0-6 / 7-13).
// ---------------------------------------------------------------------------
__global__ __launch_bounds__(256) void k1_fused(const float* __restrict__ hre,
                                                const float* __restrict__ him,
                                                float2* __restrict__ hrb,
                                                float* __restrict__ partials) {
    __shared__ float2 tile[8 * TR];     // 8 planes * 14 sym * 17 pitch = 30464 B
    __shared__ float red[4][16];

    const int tid = threadIdx.x;
    const int u = blockIdx.x >> 4;
    const int rb0 = (blockIdx.x & 15) * CRB;

    const int rb = tid & 15;
    const int k = (tid >> 4) & 7;
    const int half = tid >> 7;          // 0 or 1
    const size_t base_uk = (size_t)(u * 8 + k) * (size_t)(NSYM * NSC);

    // Phase A: load + average 12 subcarriers -> LDS tile
    for (int m = 0; m < 7; m++) {
        const int sym = half * 7 + m;
        size_t base = base_uk + (size_t)sym * NSC + (size_t)(rb0 + rb) * 12;
        const float4* pr = (const float4*)(hre + base);
        const float4* pi = (const float4*)(him + base);
        float4 r0 = pr[0], r1 = pr[1], r2 = pr[2];
        float4 i0 = pi[0], i1 = pi[1], i2 = pi[2];
        float sre = ((r0.x + r0.y) + (r0.z + r0.w) + (r1.x + r1.y) +
                     (r1.z + r1.w) + (r2.x + r2.y) + (r2.z + r2.w)) * (1.0f / 12.0f);
        float sim = ((i0.x + i0.y) + (i0.z + i0.w) + (i1.x + i1.y) +
                     (i1.z + i1.w) + (i2.x + i2.y) + (i2.z + i2.w)) * (1.0f / 12.0f);
        tile[k * TR + sym * TP + rb] = make_float2(sre, sim);
    }
    __syncthreads();

    // Phase B1: transposed writeout (8 planes * 16 rb * 14 sym = 1792 float2)
    for (int idx = tid; idx < 8 * CRB * NSYM; idx += 256) {
        int kk = idx / (CRB * NSYM);
        int rem = idx - kk * (CRB * NSYM);
        int rbw = rem / NSYM;
        int sym = rem - rbw * NSYM;
        hrb[kk * PLANE + (rb0 + rbw) * NUS + u * NSYM + sym] =
            tile[kk * TR + sym * TP + rbw];
    }

    // Phase B2: Gram over this block's 224 points (16 rb * 14 sym)
    const int pa[6] = {0, 0, 0, 1, 1, 2};
    const int pb[6] = {1, 2, 3, 2, 3, 3};
    float acc[16];
#pragma unroll
    for (int i = 0; i < 16; i++) acc[i] = 0.0f;

    if (tid < CRB * NSYM) {
        const int sym = tid >> 4;       // tid/16 (CRB=16)
        const int prb = tid & 15;
        float2 x[8];
#pragma unroll
        for (int kk = 0; kk < 8; kk++) x[kk] = tile[kk * TR + sym * TP + prb];

#pragma unroll
        for (int t = 0; t < 4; t++) {
            acc[t] = x[t].x * x[t].x + x[t].y * x[t].y +
                     x[4 + t].x * x[4 + t].x + x[4 + t].y * x[4 + t].y;
        }
#pragma unroll
        for (int q = 0; q < 6; q++) {
            int a = pa[q], bb = pb[q];
            acc[4 + 2 * q] = x[a].x * x[bb].x + x[a].y * x[bb].y +
                             x[4 + a].x * x[4 + bb].x + x[4 + a].y * x[4 + bb].y;
            acc[5 + 2 * q] = x[a].y * x[bb].x - x[a].x * x[bb].y +
                             x[4 + a].y * x[4 + bb].x - x[4 + a].x * x[4 + bb].y;
        }
    }

    // all threads participate in the wave reduction
#pragma unroll
    for (int m = 1; m < 64; m <<= 1) {
#pragma unroll
        for (int i = 0; i < 16; i++) acc[i] += __shfl_xor(acc[i], m);
    }
    const int lane = tid & 63;
    const int wv = tid >> 6;
    if (lane == 0) {
#pragma unroll
        for (int i = 0; i < 16; i++) red[wv][i] = acc[i];
    }
    __syncthreads();
    if (tid < 16) {
        partials[blockIdx.x * 16 + tid] =
            red[0][tid] + red[1][tid] + red[2][tid] + red[3][tid];
    }
}

// ---------------------------------------------------------------------------
// Kernel 3: G reduction + per-rb rate for all 32 precoders, argmax, outputs.
// Grid 256 (one block per rb) x 512 threads (16 threads per codebook c).
// ---------------------------------------------------------------------------
__global__ __launch_bounds__(512) void k3_rate(const float2* __restrict__ hrb,
                                               const float* __restrict__ partials,
                                               float* __restrict__ out,
                                               int out_size) {
    __shared__ float2 tile[NUS * 9];   // [us*9 + k], slot 8 = pad
    __shared__ float Gs[16];
    __shared__ float redg[16][17];
    __shared__ float nv_s[NC];
    __shared__ float cbr_s[NC][4], cbi_s[NC][4];
    __shared__ float rate_s[NC];

    const int rb = blockIdx.x;
    const int tid = threadIdx.x;

    // stage this rb's 448 points x 8 planes into LDS (coalesced)
    for (int idx = tid; idx < NUS * 8; idx += 512) {
        int k = idx / NUS;
        int us = idx - k * NUS;
        tile[us * 9 + k] = hrb[k * PLANE + rb * NUS + us];
    }

    // codebook table (independent of G)
    if (tid < NC) {
        const int l = tid >> 2, n = tid & 3;
        float wr, wi;
        const float SQ = 0.70710678118654752f;
        switch (l) {
            case 0: wr = 1.f;  wi = 0.f;  break;
            case 1: wr = SQ;   wi = SQ;   break;
            case 2: wr = 0.f;  wi = 1.f;  break;
            case 3: wr = -SQ;  wi = SQ;   break;
            case 4: wr = -1.f; wi = 0.f;  break;
            case 5: wr = -SQ;  wi = -SQ;  break;
            case 6: wr = 0.f;  wi = -1.f; break;
            default: wr = SQ;  wi = -SQ;  break;
        }
        float phr = (n == 0) ? 1.f : (n == 2) ? -1.f : 0.f;
        float phi = (n == 1) ? 1.f : (n == 3) ? -1.f : 0.f;
        cbr_s[tid][0] = 1.f;  cbi_s[tid][0] = 0.f;
        cbr_s[tid][1] = wr;   cbi_s[tid][1] = wi;
        cbr_s[tid][2] = phr;  cbi_s[tid][2] = phi;
        cbr_s[tid][3] = phr * wr - phi * wi;
        cbi_s[tid][3] = phr * wi + phi * wr;
    }

    // reduce 512x16 Gram partials -> Gs[16]
    if (tid < 256) {
        const int col = tid & 15;
        const int grp = tid >> 4;     // 16 groups x 32 rows
        float s = 0.0f;
#pragma unroll
        for (int m = 0; m < 32; m++) s += partials[(grp * 32 + m) * 16 + col];
        redg[grp][col] = s;
    }
    __syncthreads();
    if (tid < 16) {
        float v = 0.0f;
#pragma unroll
        for (int g = 0; g < 16; g++) v += redg[g][tid];
        Gs[tid] = v;
    }
    __syncthreads();

    // n_var[c] = (sum_t G_tt + 2*sum_{t<t'} Re(cb_t conj(cb_t') G[t,t'])) / (NPOINT*10)
    if (tid < NC) {
        float s = Gs[0] + Gs[1] + Gs[2] + Gs[3];
        const int pa[6] = {0, 0, 0, 1, 1, 2};
        const int pb[6] = {1, 2, 3, 2, 3, 3};
#pragma unroll
        for (int q = 0; q < 6; q++) {
            float gre = Gs[4 + 2 * q], gim = Gs[5 + 2 * q];
            float car = cbr_s[tid][pa[q]], cai = cbi_s[tid][pa[q]];
            float cbrx = cbr_s[tid][pb[q]], cbix = cbi_s[tid][pb[q]];
            float zr = car * cbrx + cai * cbix;   // cb_a * conj(cb_b)
            float zi = cai * cbrx - car * cbix;
            s += 2.0f * (zr * gre - zi * gim);
        }
        nv_s[tid] = s * (1.0f / (114688.0f * 10.0f));
    }
    __syncthreads();

    const int c = tid >> 4;
    const int j = tid & 15;
    float cr[4], ci[4];
#pragma unroll
    for (int t = 0; t < 4; t++) { cr[t] = cbr_s[c][t]; ci[t] = cbi_s[c][t]; }
    const float nv = nv_s[c];

    float sum = 0.0f;
    for (int us = j; us < NUS; us += 16) {
        const float2* pt = &tile[us * 9];
        float h0r = 0.f, h0i = 0.f, h1r = 0.f, h1i = 0.f;
#pragma unroll
        for (int t = 0; t < 4; t++) {
            float2 a0 = pt[t], a1 = pt[4 + t];
            h0r += cr[t] * a0.x - ci[t] * a0.y;
            h0i += cr[t] * a0.y + ci[t] * a0.x;
            h1r += cr[t] * a1.x - ci[t] * a1.y;
            h1i += cr[t] * a1.y + ci[t] * a1.x;
        }
        float a = h0r * h0r + h0i * h0i + h1r * h1r + h1i * h1i;
        float Sr = h0r + h1r, Si = h0i + h1i;
        float p = Sr * Sr + Si * Si;
        float Q = a * a + nv * p;
        float den = nv * (a * a * a + 2.0f * a * nv * p + 2.0f * nv * nv * p);
        float sinr = (Q * Q) / den;
        sum += expf(-sinr * INV_BETA);
    }
#pragma unroll
    for (int m = 8; m >= 1; m >>= 1) sum += __shfl_xor(sum, m, 16);

    if (j == 0) {
        float es = sum * (1.0f / 448.0f);
        float avg = -BETA * logf(es);
        rate_s[c] = 0.83f * log2f(1.0f + 0.73f * avg);
    }
    __syncthreads();

    if (tid == 0) {
        float best = rate_s[0];
        int bc = 0;
        for (int cc = 1; cc < NC; cc++) {
            if (rate_s[cc] > best) { best = rate_s[cc]; bc = cc; }
        }
        if (rb < out_size) out[rb] = (float)bc;                  // PMI
        if (NRB + rb < out_size) out[NRB + rb] = best;           // rate_for_selected

        if (out_size >= 2 * NRB + 8 * NRB) {
#pragma unroll
            for (int t = 0; t < 4; t++) {
                int o = 2 * NRB + (rb * 4 + t) * 2;
                out[o] = 0.5f * cbr_s[bc][t];
                out[o + 1] = 0.5f * cbi_s[bc][t];
            }
        } else {
#pragma unroll
            for (int t = 0; t < 4; t++) {
                int o = 2 * NRB + rb * 4 + t;
                if (o < out_size) out[o] = 0.5f * cbr_s[bc][t];
            }
        }
    }
}

extern "C" void kernel_launch(void* const* d_in, const int* in_sizes, int n_in,
                              void* d_out, int out_size, void* d_ws, size_t ws_size,
                              hipStream_t stream) {
    const float* hre = (const float*)d_in[0];
    const float* him = (const float*)d_in[1];
    float* out = (float*)d_out;

    float* ws = (float*)d_ws;
    float* partials = ws;                   // 512*16 floats = 8192
    float2* hrb = (float2*)(ws + 8192);     // 8 * 114688 float2 = 7.34 MB

    k1_fused<<<512, 256, 0, stream>>>(hre, him, hrb, partials);
    k3_rate<<<256, 512, 0, stream>>>(hrb, partials, out, out_size);
}